// Round 6
// baseline (5371.747 us; speedup 1.0000x reference)
//
#include <hip/hip_runtime.h>
#include <hip/hip_fp16.h>

typedef _Float16 half8 __attribute__((ext_vector_type(8)));
typedef float floatx4 __attribute__((ext_vector_type(4)));
typedef unsigned int uintx4 __attribute__((ext_vector_type(4)));

#define INPUT  512
#define HIDDEN 1024
#define OUTPUT 256
#define BATCH  128
#define SEQ    512

// ---------------------------------------------------------------------------
// K0: transpose + fp32->fp16:  W_h [K][N] f32 -> WhT [N][K] f16
// ---------------------------------------------------------------------------
__global__ __launch_bounds__(256) void transpose_f32_to_f16(
    const float* __restrict__ in, _Float16* __restrict__ out, int K, int N) {
  __shared__ float tile[32][33];
  int bi = blockIdx.x;
  int bj = blockIdx.y;
  int cc = threadIdx.x & 31;
  int rr = threadIdx.x >> 5;
#pragma unroll
  for (int s = 0; s < 4; ++s) {
    int r = rr + 8 * s;
    tile[r][cc] = in[(size_t)(bi * 32 + r) * N + bj * 32 + cc];
  }
  __syncthreads();
#pragma unroll
  for (int s = 0; s < 4; ++s) {
    int nl = rr + 8 * s;
    out[(size_t)(bj * 32 + nl) * K + bi * 32 + cc] = (_Float16)tile[cc][nl];
  }
}

// ---------------------------------------------------------------------------
// K0b: pack W_in [512][1024] f32 into MFMA B-fragment order (fp16):
// P[(k>>5)*32768 + n*32 + (k&31)] = W[k][n]
// -> a wave's B-frag load (lane l: n=base+l15, k-quad=(l>>4)*8) is one
//    fully-coalesced 1KB tile instead of a 16-line gather.
// ---------------------------------------------------------------------------
__global__ __launch_bounds__(256) void pack_win(
    const float* __restrict__ W, _Float16* __restrict__ P) {
  int idx = blockIdx.x * 256 + threadIdx.x;   // 0..524287
  int k = idx >> 10, n = idx & 1023;
  P[((size_t)(k >> 5) << 15) + (n << 5) + (k & 31)] = (_Float16)W[idx];
}

// ---------------------------------------------------------------------------
// K1: xin[S][B][H] = x @ W_in  (time-major).  64x128 tile, 4 waves,
// 8 ntiles/wave, packed-fragment B loads.  XCD-sliced bm swizzle.
// ---------------------------------------------------------------------------
__global__ __launch_bounds__(256) void xin_gemm(
    const float* __restrict__ x, const _Float16* __restrict__ WinP,
    _Float16* __restrict__ xin) {
  int bid = blockIdx.x;                     // 8192 blocks
  int bm = (bid & 7) * 128 + ((bid >> 3) & 127);   // 0..1023
  int bn = bid >> 10;                       // 0..7
  int tid = threadIdx.x;
  int l = tid & 63;
  int w = tid >> 6;
  int l15 = l & 15;
  int lk = (l >> 4) << 3;

  int rowbase = bm * 64 + w * 16;
  int colbase = bn * 128;

  floatx4 acc[8];
#pragma unroll
  for (int nt = 0; nt < 8; ++nt) acc[nt] = (floatx4){0.f, 0.f, 0.f, 0.f};

  const float* xrow = x + (size_t)(rowbase + l15) * INPUT;

  for (int k0 = 0; k0 < INPUT; k0 += 32) {
    int ak = k0 + lk;
    float4 xa = *reinterpret_cast<const float4*>(xrow + ak);
    float4 xb = *reinterpret_cast<const float4*>(xrow + ak + 4);
    half8 a;
    a[0] = (_Float16)xa.x; a[1] = (_Float16)xa.y;
    a[2] = (_Float16)xa.z; a[3] = (_Float16)xa.w;
    a[4] = (_Float16)xb.x; a[5] = (_Float16)xb.y;
    a[6] = (_Float16)xb.z; a[7] = (_Float16)xb.w;
    const _Float16* pq = WinP + ((size_t)(k0 >> 5) << 15) + l15 * 32 + lk;
#pragma unroll
    for (int nt = 0; nt < 8; ++nt) {
      half8 b = *reinterpret_cast<const half8*>(pq + (colbase + nt * 16) * 32);
      acc[nt] = __builtin_amdgcn_mfma_f32_16x16x32_f16(a, b, acc[nt], 0, 0, 0);
    }
  }

  int orow = rowbase + ((l >> 4) << 2);
#pragma unroll
  for (int nt = 0; nt < 8; ++nt)
#pragma unroll
    for (int i = 0; i < 4; ++i) {
      int r = orow + i;
      int b = r >> 9;
      int s = r & 511;
      xin[((size_t)s * BATCH + b) * HIDDEN + colbase + nt * 16 + l15] =
          (_Float16)acc[nt][i];
    }
}

// ---------------------------------------------------------------------------
// K2: persistent recurrence.  64 blocks = 8 groups (16 rows) x 8 col-blocks
// (128 cols).  Tagged-word exchange (R2/R4 proven agent-scope semantics) +
// per-wave monotonic "done" hint words (spin on 1 cacheline, not 64KB data;
// tags stay the ground truth).  Poll asm fuses issue+waitcnt in ONE block
// (R5 crash fix: no in-flight loads can outlive their asm statement).
// xin prefetched 4 steps ahead with compiler-tracked loads.
// ---------------------------------------------------------------------------
__global__ __launch_bounds__(512) void liquid_scan(
    const _Float16* __restrict__ xin,   // [S][B][H]
    const _Float16* __restrict__ WhT,   // [H n][H k]
    const float* __restrict__ b_in, const float* __restrict__ b_h,
    const float* __restrict__ tau,
    unsigned int* hbuf,                 // [2][8][16][1024] tagged u32
    float* __restrict__ hfinal,         // [B][H] f32
    unsigned int* done) {               // [8][64], memset-0
  int blk = blockIdx.x;
  int m = blk & 7;                  // batch group -> XCD m (perf heuristic)
  int j = blk >> 3;                 // col block, 0..7
  int tid = threadIdx.x;
  int l = tid & 63;
  int w = tid >> 6;                 // 0..7
  int np = w & 3;
  int kg = w >> 2;
  int l15 = l & 15;
  int lk = (l >> 4) << 3;

  __shared__ _Float16 Ald[16][1032];
  __shared__ float part[2][4][4][64];  // [dest kg][np][i][lane]

  // ---- stationary W_h: two ntiles per wave (128 VGPR) ----
  int c0 = j * 128 + np * 32 + l15;
  half8 bf0[16], bf1[16];
  {
    const _Float16* wb0 = WhT + (size_t)c0 * HIDDEN + kg * 512 + lk;
    const _Float16* wb1 = wb0 + 16 * HIDDEN;
#pragma unroll
    for (int q = 0; q < 16; ++q) {
      bf0[q] = *reinterpret_cast<const half8*>(wb0 + q * 32);
      bf1[q] = *reinterpret_cast<const half8*>(wb1 + q * 32);
    }
  }

  int ecol = j * 128 + np * 32 + kg * 16 + l15;   // wave's epilogue cols
  float bias_c = b_in[ecol] + b_h[ecol];
  float invtau_c = 1.0f / tau[ecol];
  float hown[4] = {0.f, 0.f, 0.f, 0.f};
  int erow_i = (l >> 4) << 2;
  int erow0 = m * 16 + erow_i;

  const int srow = tid >> 8;
  const int scol4 = (tid & 255) * 4;
  unsigned int* gbase = hbuf + m * 16384 + tid * 4;
  const unsigned int* dspin = done + m * 64 + l;         // 64 hint words
  unsigned int* dstore = done + m * 64 + j * 8 + w;      // this wave's word

  // ---- xin: 4-step register pipeline (compiler-tracked loads) ----
  _Float16 xq[4][4];
#pragma unroll
  for (int p = 0; p < 4; ++p)
#pragma unroll
    for (int i = 0; i < 4; ++i)
      xq[p][i] = xin[((size_t)p * BATCH + erow0 + i) * HIDDEN + ecol];

  for (int tb = 0; tb < SEQ; tb += 4) {
    _Float16 xn[4][4];
#pragma unroll
    for (int ph = 0; ph < 4; ++ph) {
      const int t = tb + ph;

      if (t > 0) {
        // 1) spin on the done hint (one line; producers >= t)
        for (;;) {
          unsigned dv = __hip_atomic_load(dspin, __ATOMIC_RELAXED,
                                          __HIP_MEMORY_SCOPE_AGENT);
          if (__all((int)(dv >= (unsigned)t))) break;
          __builtin_amdgcn_s_sleep(1);
        }
        // 2) read tagged data (~1 round); tags are ground truth
        unsigned int* bp = gbase + (size_t)(t & 1) * 131072;
        const unsigned want = (unsigned)t;
        uintx4 q0, q1, q2, q3, q4, q5, q6, q7;
        for (;;) {
          asm volatile(
              "global_load_dwordx4 %0, %8, off sc1\n\t"
              "global_load_dwordx4 %1, %9, off sc1\n\t"
              "global_load_dwordx4 %2, %10, off sc1\n\t"
              "global_load_dwordx4 %3, %11, off sc1\n\t"
              "global_load_dwordx4 %4, %12, off sc1\n\t"
              "global_load_dwordx4 %5, %13, off sc1\n\t"
              "global_load_dwordx4 %6, %14, off sc1\n\t"
              "global_load_dwordx4 %7, %15, off sc1\n\t"
              "s_waitcnt vmcnt(0)"
              : "=&v"(q0), "=&v"(q1), "=&v"(q2), "=&v"(q3),
                "=&v"(q4), "=&v"(q5), "=&v"(q6), "=&v"(q7)
              : "v"(bp), "v"(bp + 2048), "v"(bp + 4096), "v"(bp + 6144),
                "v"(bp + 8192), "v"(bp + 10240), "v"(bp + 12288),
                "v"(bp + 14336)
              : "memory");
          unsigned bad = 0;
#define CH(Q) bad |= ((Q[0] ^ want) | (Q[1] ^ want) | (Q[2] ^ want) | \
                      (Q[3] ^ want)) & 0xFFFFu;
          CH(q0) CH(q1) CH(q2) CH(q3) CH(q4) CH(q5) CH(q6) CH(q7)
#undef CH
          if (!__any((int)(bad != 0u))) break;
          __builtin_amdgcn_s_sleep(1);
        }
        // 3) strip tags -> LDS
#define STRIP(Q, I)                                                          \
        {                                                                    \
          unsigned lo = __builtin_amdgcn_perm(Q[1], Q[0], 0x07060302u);      \
          unsigned hi = __builtin_amdgcn_perm(Q[3], Q[2], 0x07060302u);      \
          unsigned int* d =                                                  \
              reinterpret_cast<unsigned int*>(&Ald[2 * I + srow][scol4]);    \
          d[0] = lo; d[1] = hi;                                              \
        }
        STRIP(q0, 0) STRIP(q1, 1) STRIP(q2, 2) STRIP(q3, 3)
        STRIP(q4, 4) STRIP(q5, 5) STRIP(q6, 6) STRIP(q7, 7)
#undef STRIP
      }

      if (ph == 0) {  // prefetch xin for steps tb+4..tb+7 (full step of slack)
#pragma unroll
        for (int p = 0; p < 4; ++p) {
          int ts = tb + 4 + p; if (ts > SEQ - 1) ts = SEQ - 1;
#pragma unroll
          for (int i = 0; i < 4; ++i)
            xn[p][i] = xin[((size_t)ts * BATCH + erow0 + i) * HIDDEN + ecol];
        }
      }
      __syncthreads();  // B1: h_t staged in LDS

      floatx4 acc0 = (floatx4){0.f, 0.f, 0.f, 0.f};
      floatx4 acc1 = (floatx4){0.f, 0.f, 0.f, 0.f};
      if (t > 0) {
        const int kb = kg * 512 + lk;
#pragma unroll
        for (int q = 0; q < 16; ++q) {
          half8 a = *reinterpret_cast<const half8*>(&Ald[l15][kb + q * 32]);
          acc0 = __builtin_amdgcn_mfma_f32_16x16x32_f16(a, bf0[q], acc0, 0, 0, 0);
          acc1 = __builtin_amdgcn_mfma_f32_16x16x32_f16(a, bf1[q], acc1, 0, 0, 0);
        }
      }
      if (kg == 0) {
#pragma unroll
        for (int i = 0; i < 4; ++i) part[1][np][i][l] = acc1[i];
      } else {
#pragma unroll
        for (int i = 0; i < 4; ++i) part[0][np][i][l] = acc0[i];
      }
      __syncthreads();  // B2: partials swapped; protects Ald WAR

      unsigned int* outb = hbuf + (size_t)((t + 1) & 1) * 131072 + m * 16384;
#pragma unroll
      for (int i = 0; i < 4; ++i) {
        float mine = (kg == 0) ? acc0[i] : acc1[i];
        float pre = mine + part[kg][np][i][l] + (float)xq[ph][i] + bias_c;
        float xc = fminf(fmaxf(pre, -15.f), 15.f);
        float e = __expf(2.f * xc);
        float dx = (e - 1.f) / (e + 1.f);
        float hn = hown[i] + (dx - hown[i]) * invtau_c;
        hown[i] = hn;
        if (t < SEQ - 1) {
          unsigned short hb = __builtin_bit_cast(unsigned short, (_Float16)hn);
          unsigned word = ((unsigned)hb << 16) | (unsigned)(t + 1);
          __hip_atomic_store(outb + (erow_i + i) * 1024 + ecol, word,
                             __ATOMIC_RELAXED, __HIP_MEMORY_SCOPE_AGENT);
        } else {
          hfinal[(size_t)(erow0 + i) * HIDDEN + ecol] = hn;
        }
      }
      // per-wave done hint (program order after this wave's tag stores)
      if (l == 0 && t < SEQ - 1)
        __hip_atomic_store(dstore, (unsigned)(t + 1), __ATOMIC_RELAXED,
                           __HIP_MEMORY_SCOPE_AGENT);
    }
#pragma unroll
    for (int p = 0; p < 4; ++p)
#pragma unroll
      for (int i = 0; i < 4; ++i) xq[p][i] = xn[p][i];
  }
}

// ---------------------------------------------------------------------------
// K3: out[B][256] = hfinal @ W_out + b_out
// ---------------------------------------------------------------------------
__global__ __launch_bounds__(256) void out_gemm(
    const float* __restrict__ hfinal, const float* __restrict__ Wout,
    const float* __restrict__ bout, float* __restrict__ out) {
  int b0 = blockIdx.x * 2;
  int o = threadIdx.x;
  float a0 = 0.f, a1 = 0.f;
  for (int k = 0; k < HIDDEN; ++k) {
    float wv = Wout[(size_t)k * OUTPUT + o];
    a0 += hfinal[(size_t)b0 * HIDDEN + k] * wv;
    a1 += hfinal[(size_t)(b0 + 1) * HIDDEN + k] * wv;
  }
  out[(size_t)b0 * OUTPUT + o] = a0 + bout[o];
  out[(size_t)(b0 + 1) * OUTPUT + o] = a1 + bout[o];
}

// ---------------------------------------------------------------------------
extern "C" void kernel_launch(void* const* d_in, const int* in_sizes, int n_in,
                              void* d_out, int out_size, void* d_ws,
                              size_t ws_size, hipStream_t stream) {
  const float* x     = (const float*)d_in[0];
  const float* W_in  = (const float*)d_in[1];
  const float* b_in  = (const float*)d_in[2];
  const float* W_h   = (const float*)d_in[3];
  const float* b_h   = (const float*)d_in[4];
  const float* tau   = (const float*)d_in[5];
  const float* W_out = (const float*)d_in[6];
  const float* b_out = (const float*)d_in[7];
  float* out = (float*)d_out;

  char* ws = (char*)d_ws;
  _Float16* xin = (_Float16*)ws;  ws += (size_t)BATCH * SEQ * HIDDEN * 2;  // 134MB
  _Float16* WinP = (_Float16*)ws; ws += (size_t)INPUT * HIDDEN * 2;        // 1MB
  _Float16* WhT = (_Float16*)ws;  ws += (size_t)HIDDEN * HIDDEN * 2;       // 2MB
  unsigned int* hbuf = (unsigned int*)ws;
  ws += (size_t)2 * BATCH * HIDDEN * 4;                                    // 1MB
  float* hfin = (float*)ws;       ws += (size_t)BATCH * HIDDEN * 4;        // 512KB
  unsigned int* done = (unsigned int*)ws; ws += 8 * 64 * 4;                // 2KB

  hipMemsetAsync(hbuf, 0, (size_t)2 * BATCH * HIDDEN * 4, stream);
  hipMemsetAsync(done, 0, 8 * 64 * 4, stream);

  transpose_f32_to_f16<<<dim3(HIDDEN / 32, HIDDEN / 32), 256, 0, stream>>>(
      W_h, WhT, HIDDEN, HIDDEN);
  pack_win<<<(INPUT * HIDDEN) / 256, 256, 0, stream>>>(W_in, WinP);

  xin_gemm<<<(BATCH * SEQ / 64) * (HIDDEN / 128), 256, 0, stream>>>(x, WinP,
                                                                    xin);

  liquid_scan<<<64, 512, 0, stream>>>(xin, WhT, b_in, b_h, tau, hbuf, hfin,
                                      done);

  out_gemm<<<BATCH / 2, OUTPUT, 0, stream>>>(hfin, W_out, b_out, out);
}

// Round 7
// 1538.805 us; speedup vs baseline: 3.4909x; 3.4909x over previous
//
#include <hip/hip_runtime.h>
#include <hip/hip_fp16.h>

typedef _Float16 half8 __attribute__((ext_vector_type(8)));
typedef float floatx4 __attribute__((ext_vector_type(4)));
typedef unsigned int uintx4 __attribute__((ext_vector_type(4)));

#define INPUT  512
#define HIDDEN 1024
#define OUTPUT 256
#define BATCH  128
#define SEQ    512

// ---------------------------------------------------------------------------
// K0: transpose + fp32->fp16:  W_h [K][N] f32 -> WhT [N][K] f16
// ---------------------------------------------------------------------------
__global__ __launch_bounds__(256) void transpose_f32_to_f16(
    const float* __restrict__ in, _Float16* __restrict__ out, int K, int N) {
  __shared__ float tile[32][33];
  int bi = blockIdx.x;
  int bj = blockIdx.y;
  int cc = threadIdx.x & 31;
  int rr = threadIdx.x >> 5;
#pragma unroll
  for (int s = 0; s < 4; ++s) {
    int r = rr + 8 * s;
    tile[r][cc] = in[(size_t)(bi * 32 + r) * N + bj * 32 + cc];
  }
  __syncthreads();
#pragma unroll
  for (int s = 0; s < 4; ++s) {
    int nl = rr + 8 * s;
    out[(size_t)(bj * 32 + nl) * K + bi * 32 + cc] = (_Float16)tile[cc][nl];
  }
}

// ---------------------------------------------------------------------------
// K0b: pack W_in [512][1024] f32 into MFMA B-fragment order (fp16):
// P[(k>>5)*32768 + n*32 + (k&31)] = W[k][n]   (validated win, R6)
// ---------------------------------------------------------------------------
__global__ __launch_bounds__(256) void pack_win(
    const float* __restrict__ W, _Float16* __restrict__ P) {
  int idx = blockIdx.x * 256 + threadIdx.x;   // 0..524287
  int k = idx >> 10, n = idx & 1023;
  P[((size_t)(k >> 5) << 15) + (n << 5) + (k & 31)] = (_Float16)W[idx];
}

// ---------------------------------------------------------------------------
// K1: xin[S][B][H] = x @ W_in  (time-major). 64x128 tile, 4 waves,
// 8 ntiles/wave, packed-fragment B loads.  (validated win, R6)
// ---------------------------------------------------------------------------
__global__ __launch_bounds__(256) void xin_gemm(
    const float* __restrict__ x, const _Float16* __restrict__ WinP,
    _Float16* __restrict__ xin) {
  int bid = blockIdx.x;                     // 8192 blocks
  int bm = (bid & 7) * 128 + ((bid >> 3) & 127);   // 0..1023
  int bn = bid >> 10;                       // 0..7
  int tid = threadIdx.x;
  int l = tid & 63;
  int w = tid >> 6;
  int l15 = l & 15;
  int lk = (l >> 4) << 3;

  int rowbase = bm * 64 + w * 16;
  int colbase = bn * 128;

  floatx4 acc[8];
#pragma unroll
  for (int nt = 0; nt < 8; ++nt) acc[nt] = (floatx4){0.f, 0.f, 0.f, 0.f};

  const float* xrow = x + (size_t)(rowbase + l15) * INPUT;

  for (int k0 = 0; k0 < INPUT; k0 += 32) {
    int ak = k0 + lk;
    float4 xa = *reinterpret_cast<const float4*>(xrow + ak);
    float4 xb = *reinterpret_cast<const float4*>(xrow + ak + 4);
    half8 a;
    a[0] = (_Float16)xa.x; a[1] = (_Float16)xa.y;
    a[2] = (_Float16)xa.z; a[3] = (_Float16)xa.w;
    a[4] = (_Float16)xb.x; a[5] = (_Float16)xb.y;
    a[6] = (_Float16)xb.z; a[7] = (_Float16)xb.w;
    const _Float16* pq = WinP + ((size_t)(k0 >> 5) << 15) + l15 * 32 + lk;
#pragma unroll
    for (int nt = 0; nt < 8; ++nt) {
      half8 b = *reinterpret_cast<const half8*>(pq + (colbase + nt * 16) * 32);
      acc[nt] = __builtin_amdgcn_mfma_f32_16x16x32_f16(a, b, acc[nt], 0, 0, 0);
    }
  }

  int orow = rowbase + ((l >> 4) << 2);
#pragma unroll
  for (int nt = 0; nt < 8; ++nt)
#pragma unroll
    for (int i = 0; i < 4; ++i) {
      int r = orow + i;
      int b = r >> 9;
      int s = r & 511;
      xin[((size_t)s * BATCH + b) * HIDDEN + colbase + nt * 16 + l15] =
          (_Float16)acc[nt][i];
    }
}

// ---------------------------------------------------------------------------
// K2: persistent recurrence — R4 structure (proven 1880us) + safe deltas.
// 128 blocks = 8 batch-groups (16 rows) x 16 N-slices (64 cols).
// 8 waves = 4 ntiles x 2 K-halves; W_h slice stationary in VGPRs.
// Tagged-word exchange, direct data polling (no hint gate, no sleeps).
// Deltas vs R4: fused issue+waitcnt poll asm (R5 crash lesson); xin via
// 2-deep register pipeline issued AFTER the poll (HBM off serial path);
// balanced epilogue (each wave finalizes 2 rows, not kg0 doing 4).
// ---------------------------------------------------------------------------
__global__ __launch_bounds__(512) void liquid_scan(
    const _Float16* __restrict__ xin,   // [S][B][H]
    const _Float16* __restrict__ WhT,   // [H n][H k]
    const float* __restrict__ b_in, const float* __restrict__ b_h,
    const float* __restrict__ tau,
    unsigned int* hbuf,                 // [2][8][16][1024] tagged u32
    float* __restrict__ hfinal) {       // [B][H] f32
  int blk = blockIdx.x;
  int m = blk & 7;                  // batch group -> XCD m (perf heuristic)
  int j = blk >> 3;                 // N slice, 0..15
  int tid = threadIdx.x;
  int l = tid & 63;
  int w = tid >> 6;                 // 0..7
  int nt = w & 3;
  int kg = w >> 2;
  int l15 = l & 15;
  int lk = (l >> 4) << 3;

  __shared__ _Float16 Ald[16][1032];
  __shared__ float part[2][4][2][64];  // [dest kg][nt][i2][lane]

  // ---- stationary W_h fragments ----
  int ncol = j * 64 + nt * 16 + l15;
  half8 bfrag[16];
  {
    const _Float16* wb = WhT + (size_t)ncol * HIDDEN + kg * 512 + lk;
#pragma unroll
    for (int q = 0; q < 16; ++q)
      bfrag[q] = *reinterpret_cast<const half8*>(wb + q * 32);
  }

  float bias_c = b_in[ncol] + b_h[ncol];
  float invtau_c = 1.0f / tau[ncol];
  float hown[2] = {0.f, 0.f};
  int erow_i = (l >> 4) << 2;             // C/D row base (0,4,8,12)
  const int i0 = kg * 2;                  // this wave finalizes rows i0,i0+1
  const int r0 = m * 16 + erow_i + i0;    // global batch rows r0, r0+1

  const int srow = tid >> 8;
  const int scol4 = (tid & 255) * 4;
  unsigned int* gbase = hbuf + m * 16384 + tid * 4;

  // ---- xin 2-deep register pipeline (compiler-tracked loads) ----
  _Float16 xc[2], x1[2], xn[2];
#pragma unroll
  for (int i2 = 0; i2 < 2; ++i2) {
    xc[i2] = xin[((size_t)0 * BATCH + r0 + i2) * HIDDEN + ncol];
    x1[i2] = xin[((size_t)1 * BATCH + r0 + i2) * HIDDEN + ncol];
  }

  for (int t = 0; t < SEQ; ++t) {
    if (t > 0) {
      unsigned int* bp = gbase + (size_t)(t & 1) * 131072;
      const unsigned want = (unsigned)t;
      uintx4 q0, q1, q2, q3, q4, q5, q6, q7;
      for (;;) {
        // fused issue+wait: no load outlives its asm statement (R5 lesson)
        asm volatile(
            "global_load_dwordx4 %0, %8, off sc1\n\t"
            "global_load_dwordx4 %1, %9, off sc1\n\t"
            "global_load_dwordx4 %2, %10, off sc1\n\t"
            "global_load_dwordx4 %3, %11, off sc1\n\t"
            "global_load_dwordx4 %4, %12, off sc1\n\t"
            "global_load_dwordx4 %5, %13, off sc1\n\t"
            "global_load_dwordx4 %6, %14, off sc1\n\t"
            "global_load_dwordx4 %7, %15, off sc1\n\t"
            "s_waitcnt vmcnt(0)"
            : "=&v"(q0), "=&v"(q1), "=&v"(q2), "=&v"(q3),
              "=&v"(q4), "=&v"(q5), "=&v"(q6), "=&v"(q7)
            : "v"(bp), "v"(bp + 2048), "v"(bp + 4096), "v"(bp + 6144),
              "v"(bp + 8192), "v"(bp + 10240), "v"(bp + 12288),
              "v"(bp + 14336)
            : "memory");
        unsigned bad = 0;
#define CH(Q) bad |= ((Q[0] ^ want) | (Q[1] ^ want) | (Q[2] ^ want) | \
                      (Q[3] ^ want)) & 0xFFFFu;
        CH(q0) CH(q1) CH(q2) CH(q3) CH(q4) CH(q5) CH(q6) CH(q7)
#undef CH
        if (!__any((int)(bad != 0u))) break;
      }
#define STRIP(Q, I)                                                          \
      {                                                                      \
        unsigned lo = __builtin_amdgcn_perm(Q[1], Q[0], 0x07060302u);        \
        unsigned hi = __builtin_amdgcn_perm(Q[3], Q[2], 0x07060302u);        \
        unsigned int* d =                                                    \
            reinterpret_cast<unsigned int*>(&Ald[2 * I + srow][scol4]);      \
        d[0] = lo; d[1] = hi;                                                \
      }
      STRIP(q0, 0) STRIP(q1, 1) STRIP(q2, 2) STRIP(q3, 3)
      STRIP(q4, 4) STRIP(q5, 5) STRIP(q6, 6) STRIP(q7, 7)
#undef STRIP
    }

    // issue xin loads for step t+2 now — poll vmcnt(0) can never wait on
    // them (they're consumed and re-copied a full step later)
    {
      int ts = (t + 2 < SEQ) ? t + 2 : SEQ - 1;
      xn[0] = xin[((size_t)ts * BATCH + r0) * HIDDEN + ncol];
      xn[1] = xin[((size_t)ts * BATCH + r0 + 1) * HIDDEN + ncol];
    }
    __syncthreads();  // B1: h_t staged in LDS

    floatx4 acc = (floatx4){0.f, 0.f, 0.f, 0.f};
    if (t > 0) {
      const int kb = kg * 512 + lk;
#pragma unroll
      for (int q = 0; q < 16; ++q) {
        half8 a = *reinterpret_cast<const half8*>(&Ald[l15][kb + q * 32]);
        acc = __builtin_amdgcn_mfma_f32_16x16x32_f16(a, bfrag[q], acc, 0, 0, 0);
      }
    }
    // hand partner its 2 rows of my partial
    {
      const int ip = 2 - i0;  // partner's row base (kg0 -> 2,3 ; kg1 -> 0,1)
#pragma unroll
      for (int i2 = 0; i2 < 2; ++i2) part[1 - kg][nt][i2][l] = acc[ip + i2];
    }
    __syncthreads();  // B2: partials swapped; protects Ald WAR

    unsigned int* outb = hbuf + (size_t)((t + 1) & 1) * 131072 + m * 16384;
#pragma unroll
    for (int i2 = 0; i2 < 2; ++i2) {
      float pre = acc[i0 + i2] + part[kg][nt][i2][l] + (float)xc[i2] + bias_c;
      float x2 = fminf(fmaxf(pre, -15.f), 15.f);
      float e = __expf(2.f * x2);
      float dx = (e - 1.f) / (e + 1.f);
      float hn = hown[i2] + (dx - hown[i2]) * invtau_c;
      hown[i2] = hn;
      if (t < SEQ - 1) {
        unsigned short hb = __builtin_bit_cast(unsigned short, (_Float16)hn);
        unsigned word = ((unsigned)hb << 16) | (unsigned)(t + 1);
        __hip_atomic_store(outb + (erow_i + i0 + i2) * 1024 + ncol, word,
                           __ATOMIC_RELAXED, __HIP_MEMORY_SCOPE_AGENT);
      } else {
        hfinal[(size_t)(r0 + i2) * HIDDEN + ncol] = hn;
      }
    }
    // rotate xin pipeline (compiler's waitcnt lands here — a full step after
    // issue, so the latency is fully hidden)
    xc[0] = x1[0]; xc[1] = x1[1];
    x1[0] = xn[0]; x1[1] = xn[1];
  }
}

// ---------------------------------------------------------------------------
// K3: out[B][256] = hfinal @ W_out + b_out
// ---------------------------------------------------------------------------
__global__ __launch_bounds__(256) void out_gemm(
    const float* __restrict__ hfinal, const float* __restrict__ Wout,
    const float* __restrict__ bout, float* __restrict__ out) {
  int b0 = blockIdx.x * 2;
  int o = threadIdx.x;
  float a0 = 0.f, a1 = 0.f;
  for (int k = 0; k < HIDDEN; ++k) {
    float wv = Wout[(size_t)k * OUTPUT + o];
    a0 += hfinal[(size_t)b0 * HIDDEN + k] * wv;
    a1 += hfinal[(size_t)(b0 + 1) * HIDDEN + k] * wv;
  }
  out[(size_t)b0 * OUTPUT + o] = a0 + bout[o];
  out[(size_t)(b0 + 1) * OUTPUT + o] = a1 + bout[o];
}

// ---------------------------------------------------------------------------
extern "C" void kernel_launch(void* const* d_in, const int* in_sizes, int n_in,
                              void* d_out, int out_size, void* d_ws,
                              size_t ws_size, hipStream_t stream) {
  const float* x     = (const float*)d_in[0];
  const float* W_in  = (const float*)d_in[1];
  const float* b_in  = (const float*)d_in[2];
  const float* W_h   = (const float*)d_in[3];
  const float* b_h   = (const float*)d_in[4];
  const float* tau   = (const float*)d_in[5];
  const float* W_out = (const float*)d_in[6];
  const float* b_out = (const float*)d_in[7];
  float* out = (float*)d_out;

  char* ws = (char*)d_ws;
  _Float16* xin = (_Float16*)ws;  ws += (size_t)BATCH * SEQ * HIDDEN * 2;  // 134MB
  _Float16* WinP = (_Float16*)ws; ws += (size_t)INPUT * HIDDEN * 2;        // 1MB
  _Float16* WhT = (_Float16*)ws;  ws += (size_t)HIDDEN * HIDDEN * 2;       // 2MB
  unsigned int* hbuf = (unsigned int*)ws;
  ws += (size_t)2 * BATCH * HIDDEN * 4;                                    // 1MB
  float* hfin = (float*)ws;       ws += (size_t)BATCH * HIDDEN * 4;        // 512KB

  // zero tags (tag 0 is never polled: t=0 skips the MFMA since h_0 = 0)
  hipMemsetAsync(hbuf, 0, (size_t)2 * BATCH * HIDDEN * 4, stream);

  transpose_f32_to_f16<<<dim3(HIDDEN / 32, HIDDEN / 32), 256, 0, stream>>>(
      W_h, WhT, HIDDEN, HIDDEN);
  pack_win<<<(INPUT * HIDDEN) / 256, 256, 0, stream>>>(W_in, WinP);

  xin_gemm<<<(BATCH * SEQ / 64) * (HIDDEN / 128), 256, 0, stream>>>(x, WinP,
                                                                    xin);

  liquid_scan<<<128, 512, 0, stream>>>(xin, WhT, b_in, b_h, tau, hbuf, hfin);

  out_gemm<<<BATCH / 2, OUTPUT, 0, stream>>>(hfin, W_out, b_out, out);
}